// Round 11
// baseline (217.860 us; speedup 1.0000x reference)
//
#include <hip/hip_runtime.h>
#include <hip/hip_bf16.h>

#define N_NODES 100000
#define N_EDGES 3200000
#define IN_F 256
#define OUT_F 128

#define RPB 64            // rows per bucket
#define NBIN 1563         // ceil(100000/64); bin = row >> 6
#define NBC  1000         // coarse pass blocks
#define CHUNK 3200        // edges per coarse block (1000*3200 = 3.2M exactly, %4==0)
#define GEMM_BLOCKS 782   // (N_NODES + 127) / 128
#define BPT 7             // bins per thread in pass C local scan (7*256 >= NBIN)
#define CAP 4096          // LDS edge capacity per bucket (mean 2048, sigma ~45)

typedef __attribute__((ext_vector_type(8))) short bf16x8;
typedef __attribute__((ext_vector_type(4))) float f32x4;

union U4BF { uint4 u; bf16x8 v; };

__device__ inline unsigned short f2bf(float f) {
    return __bfloat16_as_ushort(__float2bfloat16(f));
}
__device__ inline unsigned pk2(float a, float b) {
    unsigned la = __bfloat16_as_ushort(__float2bfloat16(a));
    unsigned lb = __bfloat16_as_ushort(__float2bfloat16(b));
    return la | (lb << 16);
}

// -------------------- Kernel 0: w -> frag-ordered bf16 --------------------
__global__ __launch_bounds__(256) void conv_w_kernel(
    const float* __restrict__ w, uint4* __restrict__ wbfF)
{
    int tid = blockIdx.x * 256 + threadIdx.x;   // 0..4095
    int ks = tid >> 9;
    int fn = (tid >> 6) & 7;
    int l  = tid & 63;
    int c  = fn * 16 + (l & 15);
    int k0 = ks * 32 + (l >> 4) * 8;
    const float* wp = w + (size_t)k0 * OUT_F + c;
    uint4 u;
    u.x = pk2(wp[0 * OUT_F], wp[1 * OUT_F]);
    u.y = pk2(wp[2 * OUT_F], wp[3 * OUT_F]);
    u.z = pk2(wp[4 * OUT_F], wp[5 * OUT_F]);
    u.w = pk2(wp[6 * OUT_F], wp[7 * OUT_F]);
    wbfF[tid] = u;
}

// -------------------- Kernel 1: fused GEMM (blocks 0..781) + coarse hist ----
__global__ __launch_bounds__(256) void gemm_hist_kernel(
    const float* __restrict__ x, const uint4* __restrict__ wbfF,
    unsigned short* __restrict__ h,
    const int* __restrict__ erow, int* __restrict__ cntmat)
{
    __shared__ __align__(16) char smem[65536];
    const int t = threadIdx.x;

    if (blockIdx.x < GEMM_BLOCKS) {
        // ================= GEMM path =================
        uint4* bsh = (uint4*)smem;
        const int lane = t & 63;
        const int wid  = t >> 6;
        const int brow = blockIdx.x * 128;
        const int ln   = lane & 15;
        const int kb   = lane >> 4;

#pragma unroll
        for (int i = 0; i < 16; ++i) bsh[i * 256 + t] = wbfF[i * 256 + t];

        int r0 = brow + wid * 32 + ln;
        int r1 = r0 + 16;
        const float* a0p = x + (size_t)(r0 < N_NODES ? r0 : N_NODES - 1) * IN_F;
        const float* a1p = x + (size_t)(r1 < N_NODES ? r1 : N_NODES - 1) * IN_F;

        f32x4 acc[2][8] = {};
        __syncthreads();

#pragma unroll
        for (int ks = 0; ks < 8; ++ks) {
            const int k = ks * 32 + kb * 8;
            U4BF a0, a1;
            {
                float4 p = *(const float4*)(a0p + k);
                float4 q = *(const float4*)(a0p + k + 4);
                a0.u.x = pk2(p.x, p.y); a0.u.y = pk2(p.z, p.w);
                a0.u.z = pk2(q.x, q.y); a0.u.w = pk2(q.z, q.w);
            }
            {
                float4 p = *(const float4*)(a1p + k);
                float4 q = *(const float4*)(a1p + k + 4);
                a1.u.x = pk2(p.x, p.y); a1.u.y = pk2(p.z, p.w);
                a1.u.z = pk2(q.x, q.y); a1.u.w = pk2(q.z, q.w);
            }
            U4BF b[8];
#pragma unroll
            for (int fn = 0; fn < 8; ++fn)
                b[fn].u = bsh[(ks * 8 + fn) * 64 + lane];
#pragma unroll
            for (int fn = 0; fn < 8; ++fn) {
                acc[0][fn] = __builtin_amdgcn_mfma_f32_16x16x32_bf16(
                    a0.v, b[fn].v, acc[0][fn], 0, 0, 0);
                acc[1][fn] = __builtin_amdgcn_mfma_f32_16x16x32_bf16(
                    a1.v, b[fn].v, acc[1][fn], 0, 0, 0);
            }
        }

#pragma unroll
        for (int fm = 0; fm < 2; ++fm) {
#pragma unroll
            for (int r = 0; r < 4; ++r) {
                int grow = brow + wid * 32 + fm * 16 + (lane >> 4) * 4 + r;
                if (grow < N_NODES) {
                    unsigned short* dst = h + (size_t)grow * OUT_F + ln;
#pragma unroll
                    for (int fn = 0; fn < 8; ++fn)
                        dst[fn * 16] = f2bf(acc[fm][fn][r]);
                }
            }
        }
    } else {
        // ================= Pass A path: coarse LDS histogram =================
        int* lhist = (int*)smem;
        const int b = blockIdx.x - GEMM_BLOCKS;
        for (int i = t; i < NBIN; i += 256) lhist[i] = 0;
        __syncthreads();

        const int base = b * CHUNK;
        const int end  = min(base + CHUNK, N_EDGES);
        for (int i = base + t * 4; i < end; i += 1024) {
            int4 r = *(const int4*)(erow + i);
            atomicAdd(&lhist[r.x >> 6], 1);
            atomicAdd(&lhist[r.y >> 6], 1);
            atomicAdd(&lhist[r.z >> 6], 1);
            atomicAdd(&lhist[r.w >> 6], 1);
        }
        __syncthreads();

        int* dst = cntmat + (size_t)b * NBIN;
        for (int j = t; j < NBIN; j += 256) dst[j] = lhist[j];
    }
}

// -------------------- Pass B: per-bin exclusive scan over 1000 blocks ----------
// Thread t owns blocks 4t..4t+3 of column j.
__global__ __launch_bounds__(256) void pass_b_kernel(
    const int* __restrict__ cntmat, int* __restrict__ blockbase,
    int* __restrict__ tot)
{
    __shared__ int sh[256];
    const int t = threadIdx.x;
    const int j = blockIdx.x;
    int c[4];
    int ps = 0;
#pragma unroll
    for (int i = 0; i < 4; ++i) {
        int bb = 4 * t + i;
        c[i] = (bb < NBC) ? cntmat[(size_t)bb * NBIN + j] : 0;
        ps += c[i];
    }
    sh[t] = ps;
    __syncthreads();
    for (int off = 1; off < 256; off <<= 1) {
        int add = (t >= off) ? sh[t - off] : 0;
        __syncthreads();
        sh[t] += add;
        __syncthreads();
    }
    int excl = sh[t] - ps;
#pragma unroll
    for (int i = 0; i < 4; ++i) {
        int bb = 4 * t + i;
        if (bb < NBC) { blockbase[(size_t)bb * NBIN + j] = excl; excl += c[i]; }
    }
    if (t == 255) tot[j] = sh[255];
}

// -------------------- Pass B2: exclusive scan of 1563 bucket totals ------------
__global__ __launch_bounds__(1024) void pass_b2_kernel(
    const int* __restrict__ tot, int* __restrict__ bucket_base)
{
    __shared__ int sh[1024];
    const int t = threadIdx.x;
    const int i0 = 2 * t, i1 = 2 * t + 1;
    int v0 = (i0 < NBIN) ? tot[i0] : 0;
    int v1 = (i1 < NBIN) ? tot[i1] : 0;
    int ps = v0 + v1;
    sh[t] = ps;
    __syncthreads();
    for (int off = 1; off < 1024; off <<= 1) {
        int add = (t >= off) ? sh[t - off] : 0;
        __syncthreads();
        sh[t] += add;
        __syncthreads();
    }
    int excl = sh[t] - ps;
    if (i0 <= NBIN) bucket_base[i0] = excl;
    if (i1 <= NBIN) bucket_base[i1] = excl + v0;     // i1==NBIN -> N_EDGES
}

// -------------------- Pass C: LDS counting-sort, coalesced write-out -----------
__global__ __launch_bounds__(256) void pass_c_kernel(
    const int* __restrict__ erow, const int* __restrict__ ecol,
    const float* __restrict__ eval_, const int* __restrict__ cntmat,
    const int* __restrict__ blockbase, const int* __restrict__ bucket_base,
    int2* __restrict__ tmp)
{
    __shared__ int2 skv[CHUNK];              // 25,600 B
    __shared__ unsigned short sbin[CHUNK];   // 6,400 B
    __shared__ int  cur[NBIN];               // 6,252 B
    __shared__ int  sdel[NBIN];              // 6,252 B
    __shared__ int  sscan[256];              // total ~45.5 KB -> 3 blocks/CU

    const int t = threadIdx.x;
    const int b = blockIdx.x;

    // local exclusive scan of this block's bin counts (BPT bins/thread)
    int c[BPT];
    int ps = 0;
#pragma unroll
    for (int i = 0; i < BPT; ++i) {
        int bin = t * BPT + i;
        c[i] = (bin < NBIN) ? cntmat[(size_t)b * NBIN + bin] : 0;
        ps += c[i];
    }
    sscan[t] = ps;
    __syncthreads();
    for (int off = 1; off < 256; off <<= 1) {
        int add = (t >= off) ? sscan[t - off] : 0;
        __syncthreads();
        sscan[t] += add;
        __syncthreads();
    }
    int excl = sscan[t] - ps;
#pragma unroll
    for (int i = 0; i < BPT; ++i) {
        int bin = t * BPT + i;
        if (bin < NBIN) {
            cur[bin]  = excl;
            sdel[bin] = bucket_base[bin] + blockbase[(size_t)b * NBIN + bin] - excl;
            excl += c[i];
        }
    }
    __syncthreads();

    // scatter into LDS by bin
    const int base = b * CHUNK;
    const int end  = min(base + CHUNK, N_EDGES);
    for (int i = base + t * 4; i < end; i += 1024) {
        int4   r = *(const int4*)(erow + i);
        int4   cc = *(const int4*)(ecol + i);
        float4 v = *(const float4*)(eval_ + i);
        int bin, pos;
        bin = r.x >> 6; pos = atomicAdd(&cur[bin], 1);
        skv[pos] = make_int2(cc.x | ((r.x & 63) << 17), __float_as_int(v.x));
        sbin[pos] = (unsigned short)bin;
        bin = r.y >> 6; pos = atomicAdd(&cur[bin], 1);
        skv[pos] = make_int2(cc.y | ((r.y & 63) << 17), __float_as_int(v.y));
        sbin[pos] = (unsigned short)bin;
        bin = r.z >> 6; pos = atomicAdd(&cur[bin], 1);
        skv[pos] = make_int2(cc.z | ((r.z & 63) << 17), __float_as_int(v.z));
        sbin[pos] = (unsigned short)bin;
        bin = r.w >> 6; pos = atomicAdd(&cur[bin], 1);
        skv[pos] = make_int2(cc.w | ((r.w & 63) << 17), __float_as_int(v.w));
        sbin[pos] = (unsigned short)bin;
    }
    __syncthreads();

    // coalesced copy-out: consecutive i -> consecutive global within each run
    const int n = end - base;
    for (int i = t; i < n; i += 256) {
        int2 kv = skv[i];
        tmp[sdel[sbin[i]] + i] = kv;
    }
}

// -------------------- fused D+aggregate: per-bucket fine sort (LDS) + ---------
// register-accumulated gather + bias. One 512-thr block per 64-row bucket.
__global__ __launch_bounds__(512) void fused_da_kernel(
    const int2* __restrict__ tmp, const int* __restrict__ bucket_base,
    const unsigned* __restrict__ h2, const float* __restrict__ bias,
    float* __restrict__ out)
{
    __shared__ int2 skv[CAP];      // 32 KB sorted edges (col, val)
    __shared__ int  srow[RPB];     // per-row start in skv
    __shared__ int  scnt[RPB];     // per-row count
    __shared__ int  cursor[RPB];

    const int t    = threadIdx.x;
    const int lane = t & 63;
    const int w    = t >> 6;       // wave 0..7
    const int j    = blockIdx.x;
    const int base = bucket_base[j];
    const int n    = bucket_base[j + 1] - base;

    // fine histogram (64 bins)
    if (t < RPB) cursor[t] = 0;
    __syncthreads();
    for (int i = t; i < n; i += 512)
        atomicAdd(&cursor[tmp[base + i].x >> 17], 1);
    __syncthreads();
    // exclusive scan of 64 bins (Hillis-Steele over threads 0..63)
    if (t < RPB) { scnt[t] = cursor[t]; srow[t] = cursor[t]; }
    __syncthreads();
    for (int off = 1; off < RPB; off <<= 1) {
        int add = (t >= off && t < RPB) ? srow[t - off] : 0;
        __syncthreads();
        if (t < RPB) srow[t] += add;
        __syncthreads();
    }
    if (t < RPB) { int ex = srow[t] - scnt[t]; srow[t] = ex; cursor[t] = ex; }
    __syncthreads();

    // scatter into LDS sorted by fine row (tmp L2-hot re-read)
    for (int i = t; i < n; i += 512) {
        int2 p = tmp[base + i];
        int rl = p.x >> 17;
        int pos = atomicAdd(&cursor[rl], 1);
        skv[pos] = make_int2(p.x & 0x1FFFF, p.y);
    }
    __syncthreads();

    // aggregate: wave w handles rows w*8 .. w*8+7; lane owns feats {2l, 2l+1}
    const unsigned* hb = h2 + lane;
#pragma unroll 1
    for (int rr = w * 8; rr < w * 8 + 8; ++rr) {
        int gr = j * RPB + rr;
        if (gr >= N_NODES) break;               // wave-uniform
        int s = srow[rr];
        int end = s + scnt[rr];
        float ax = 0.f, ay = 0.f;

        int e = s;
        for (; e + 7 < end; e += 8) {
            int2 p0 = skv[e];
            int2 p1 = skv[e + 1];
            int2 p2 = skv[e + 2];
            int2 p3 = skv[e + 3];
            int2 p4 = skv[e + 4];
            int2 p5 = skv[e + 5];
            int2 p6 = skv[e + 6];
            int2 p7 = skv[e + 7];
            unsigned u0 = hb[(size_t)p0.x << 6];
            unsigned u1 = hb[(size_t)p1.x << 6];
            unsigned u2 = hb[(size_t)p2.x << 6];
            unsigned u3 = hb[(size_t)p3.x << 6];
            unsigned u4 = hb[(size_t)p4.x << 6];
            unsigned u5 = hb[(size_t)p5.x << 6];
            unsigned u6 = hb[(size_t)p6.x << 6];
            unsigned u7 = hb[(size_t)p7.x << 6];
            float v0 = __int_as_float(p0.y), v1 = __int_as_float(p1.y);
            float v2 = __int_as_float(p2.y), v3 = __int_as_float(p3.y);
            float v4 = __int_as_float(p4.y), v5 = __int_as_float(p5.y);
            float v6 = __int_as_float(p6.y), v7 = __int_as_float(p7.y);
            ax = fmaf(v0, __uint_as_float(u0 << 16), ax);
            ay = fmaf(v0, __uint_as_float(u0 & 0xFFFF0000u), ay);
            ax = fmaf(v1, __uint_as_float(u1 << 16), ax);
            ay = fmaf(v1, __uint_as_float(u1 & 0xFFFF0000u), ay);
            ax = fmaf(v2, __uint_as_float(u2 << 16), ax);
            ay = fmaf(v2, __uint_as_float(u2 & 0xFFFF0000u), ay);
            ax = fmaf(v3, __uint_as_float(u3 << 16), ax);
            ay = fmaf(v3, __uint_as_float(u3 & 0xFFFF0000u), ay);
            ax = fmaf(v4, __uint_as_float(u4 << 16), ax);
            ay = fmaf(v4, __uint_as_float(u4 & 0xFFFF0000u), ay);
            ax = fmaf(v5, __uint_as_float(u5 << 16), ax);
            ay = fmaf(v5, __uint_as_float(u5 & 0xFFFF0000u), ay);
            ax = fmaf(v6, __uint_as_float(u6 << 16), ax);
            ay = fmaf(v6, __uint_as_float(u6 & 0xFFFF0000u), ay);
            ax = fmaf(v7, __uint_as_float(u7 << 16), ax);
            ay = fmaf(v7, __uint_as_float(u7 & 0xFFFF0000u), ay);
        }
        for (; e < end; ++e) {
            int2 p0 = skv[e];
            unsigned u0 = hb[(size_t)p0.x << 6];
            float v0 = __int_as_float(p0.y);
            ax = fmaf(v0, __uint_as_float(u0 << 16), ax);
            ay = fmaf(v0, __uint_as_float(u0 & 0xFFFF0000u), ay);
        }

        float2 bb = *(const float2*)(bias + lane * 2);
        *(float2*)(out + (size_t)gr * OUT_F + lane * 2) =
            make_float2(ax + bb.x, ay + bb.y);
    }
}

// -------------------- launch --------------------
extern "C" void kernel_launch(void* const* d_in, const int* in_sizes, int n_in,
                              void* d_out, int out_size, void* d_ws, size_t ws_size,
                              hipStream_t stream)
{
    const float* x     = (const float*)d_in[0];
    const int*   erow  = (const int*)d_in[1];
    const int*   ecol  = (const int*)d_in[2];
    const float* eval_ = (const float*)d_in[3];
    const float* w     = (const float*)d_in[4];
    const float* bias  = (const float*)d_in[5];
    float*       out   = (float*)d_out;

    // workspace layout (bytes):
    //   h (bf16):    0          .. 25,600,000
    //   tmp:         25,600,000 .. 51,200,000
    //   cntmat:      51,200,000 .. 57,452,000   (1000 x 1563 int)
    //   blockbase:   57,452,000 .. 63,704,000
    //   tot:         63,704,000 .. 63,710,252 -> pad 63,712,000
    //   bucket_base: 63,712,000 .. 63,718,256 -> pad 63,720,000 (1564 int)
    //   wbfF:        63,720,000 .. 63,785,536   (~63.8 MB)
    char* ws = (char*)d_ws;
    unsigned short* h           = (unsigned short*)(ws);
    int2*           tmp         = (int2*)(ws + 25600000);
    int*            cntmat      = (int*)(ws + 51200000);
    int*            blockbase   = (int*)(ws + 57452000);
    int*            tot         = (int*)(ws + 63704000);
    int*            bucket_base = (int*)(ws + 63712000);
    uint4*          wbfF        = (uint4*)(ws + 63720000);

    // 0) w -> frag-ordered bf16
    hipLaunchKernelGGL(conv_w_kernel, dim3(16), dim3(256), 0, stream, w, wbfF);

    // 1) fused: h = bf16(x@w) via MFMA  ||  coarse histogram (1563 bins)
    hipLaunchKernelGGL(gemm_hist_kernel, dim3(GEMM_BLOCKS + NBC), dim3(256), 0, stream,
                       x, wbfF, h, erow, cntmat);

    // 2) scans
    hipLaunchKernelGGL(pass_b_kernel, dim3(NBIN), dim3(256), 0, stream,
                       cntmat, blockbase, tot);
    hipLaunchKernelGGL(pass_b2_kernel, dim3(1), dim3(1024), 0, stream, tot, bucket_base);

    // 3) LDS counting-sort scatter into bucket-ordered tmp (coalesced writes)
    hipLaunchKernelGGL(pass_c_kernel, dim3(NBC), dim3(256), 0, stream,
                       erow, ecol, eval_, cntmat, blockbase, bucket_base, tmp);

    // 4) fused fine-sort + aggregate + bias
    hipLaunchKernelGGL(fused_da_kernel, dim3(NBIN), dim3(512), 0, stream,
                       tmp, bucket_base, (const unsigned*)h, bias, out);
}

// Round 12
// 197.455 us; speedup vs baseline: 1.1033x; 1.1033x over previous
//
#include <hip/hip_runtime.h>
#include <hip/hip_bf16.h>

#define N_NODES 100000
#define N_EDGES 3200000
#define IN_F 256
#define OUT_F 128

#define RPB 128           // rows per bucket
#define NBIN 782          // ceil(100000/128); bin = row >> 7
#define NBC  896          // coarse pass blocks
#define CHUNK 3572        // edges per coarse block (896*3572 >= 3.2M, %4==0)
#define GEMM_BLOCKS 782   // (N_NODES + 127) / 128
#define BPTC 4            // bins per thread in pass C local scan (4*256 >= NBIN)
#define CAP 4608          // LDS edge capacity per bucket (mean 4096, sigma ~64)

typedef __attribute__((ext_vector_type(8))) short bf16x8;
typedef __attribute__((ext_vector_type(4))) float f32x4;

union U4BF { uint4 u; bf16x8 v; };

__device__ inline unsigned short f2bf(float f) {
    return __bfloat16_as_ushort(__float2bfloat16(f));
}
__device__ inline unsigned pk2(float a, float b) {
    unsigned la = __bfloat16_as_ushort(__float2bfloat16(a));
    unsigned lb = __bfloat16_as_ushort(__float2bfloat16(b));
    return la | (lb << 16);
}

// -------------------- Kernel 0: w -> frag-ordered bf16 --------------------
__global__ __launch_bounds__(256) void conv_w_kernel(
    const float* __restrict__ w, uint4* __restrict__ wbfF)
{
    int tid = blockIdx.x * 256 + threadIdx.x;   // 0..4095
    int ks = tid >> 9;
    int fn = (tid >> 6) & 7;
    int l  = tid & 63;
    int c  = fn * 16 + (l & 15);
    int k0 = ks * 32 + (l >> 4) * 8;
    const float* wp = w + (size_t)k0 * OUT_F + c;
    uint4 u;
    u.x = pk2(wp[0 * OUT_F], wp[1 * OUT_F]);
    u.y = pk2(wp[2 * OUT_F], wp[3 * OUT_F]);
    u.z = pk2(wp[4 * OUT_F], wp[5 * OUT_F]);
    u.w = pk2(wp[6 * OUT_F], wp[7 * OUT_F]);
    wbfF[tid] = u;
}

// -------------------- Kernel 1: fused GEMM (blocks 0..781) + coarse hist ----
__global__ __launch_bounds__(256) void gemm_hist_kernel(
    const float* __restrict__ x, const uint4* __restrict__ wbfF,
    unsigned short* __restrict__ h,
    const int* __restrict__ erow, int* __restrict__ cntmat)
{
    __shared__ __align__(16) char smem[65536];
    const int t = threadIdx.x;

    if (blockIdx.x < GEMM_BLOCKS) {
        // ================= GEMM path =================
        uint4* bsh = (uint4*)smem;
        const int lane = t & 63;
        const int wid  = t >> 6;
        const int brow = blockIdx.x * 128;
        const int ln   = lane & 15;
        const int kb   = lane >> 4;

#pragma unroll
        for (int i = 0; i < 16; ++i) bsh[i * 256 + t] = wbfF[i * 256 + t];

        int r0 = brow + wid * 32 + ln;
        int r1 = r0 + 16;
        const float* a0p = x + (size_t)(r0 < N_NODES ? r0 : N_NODES - 1) * IN_F;
        const float* a1p = x + (size_t)(r1 < N_NODES ? r1 : N_NODES - 1) * IN_F;

        f32x4 acc[2][8] = {};
        __syncthreads();

#pragma unroll
        for (int ks = 0; ks < 8; ++ks) {
            const int k = ks * 32 + kb * 8;
            U4BF a0, a1;
            {
                float4 p = *(const float4*)(a0p + k);
                float4 q = *(const float4*)(a0p + k + 4);
                a0.u.x = pk2(p.x, p.y); a0.u.y = pk2(p.z, p.w);
                a0.u.z = pk2(q.x, q.y); a0.u.w = pk2(q.z, q.w);
            }
            {
                float4 p = *(const float4*)(a1p + k);
                float4 q = *(const float4*)(a1p + k + 4);
                a1.u.x = pk2(p.x, p.y); a1.u.y = pk2(p.z, p.w);
                a1.u.z = pk2(q.x, q.y); a1.u.w = pk2(q.z, q.w);
            }
            U4BF b[8];
#pragma unroll
            for (int fn = 0; fn < 8; ++fn)
                b[fn].u = bsh[(ks * 8 + fn) * 64 + lane];
#pragma unroll
            for (int fn = 0; fn < 8; ++fn) {
                acc[0][fn] = __builtin_amdgcn_mfma_f32_16x16x32_bf16(
                    a0.v, b[fn].v, acc[0][fn], 0, 0, 0);
                acc[1][fn] = __builtin_amdgcn_mfma_f32_16x16x32_bf16(
                    a1.v, b[fn].v, acc[1][fn], 0, 0, 0);
            }
        }

#pragma unroll
        for (int fm = 0; fm < 2; ++fm) {
#pragma unroll
            for (int r = 0; r < 4; ++r) {
                int grow = brow + wid * 32 + fm * 16 + (lane >> 4) * 4 + r;
                if (grow < N_NODES) {
                    unsigned short* dst = h + (size_t)grow * OUT_F + ln;
#pragma unroll
                    for (int fn = 0; fn < 8; ++fn)
                        dst[fn * 16] = f2bf(acc[fm][fn][r]);
                }
            }
        }
    } else {
        // ================= Pass A path: coarse LDS histogram =================
        int* lhist = (int*)smem;
        const int b = blockIdx.x - GEMM_BLOCKS;
        for (int i = t; i < NBIN; i += 256) lhist[i] = 0;
        __syncthreads();

        const int base = b * CHUNK;
        const int end  = min(base + CHUNK, N_EDGES);
        for (int i = base + t * 4; i < end; i += 1024) {
            int4 r = *(const int4*)(erow + i);
            atomicAdd(&lhist[r.x >> 7], 1);
            atomicAdd(&lhist[r.y >> 7], 1);
            atomicAdd(&lhist[r.z >> 7], 1);
            atomicAdd(&lhist[r.w >> 7], 1);
        }
        __syncthreads();

        int* dst = cntmat + (size_t)b * NBIN;
        for (int j = t; j < NBIN; j += 256) dst[j] = lhist[j];
    }
}

// -------------------- Pass B: per-bin exclusive scan over 896 blocks ----------
__global__ __launch_bounds__(256) void pass_b_kernel(
    const int* __restrict__ cntmat, int* __restrict__ blockbase,
    int* __restrict__ tot)
{
    __shared__ int sh[256];
    const int t = threadIdx.x;
    const int j = blockIdx.x;
    int c[4];
    int ps = 0;
#pragma unroll
    for (int i = 0; i < 4; ++i) {
        int bb = 4 * t + i;
        c[i] = (bb < NBC) ? cntmat[(size_t)bb * NBIN + j] : 0;
        ps += c[i];
    }
    sh[t] = ps;
    __syncthreads();
    for (int off = 1; off < 256; off <<= 1) {
        int add = (t >= off) ? sh[t - off] : 0;
        __syncthreads();
        sh[t] += add;
        __syncthreads();
    }
    int excl = sh[t] - ps;
#pragma unroll
    for (int i = 0; i < 4; ++i) {
        int bb = 4 * t + i;
        if (bb < NBC) { blockbase[(size_t)bb * NBIN + j] = excl; excl += c[i]; }
    }
    if (t == 255) tot[j] = sh[255];
}

// -------------------- Pass B2: exclusive scan of 782 bucket totals ------------
__global__ __launch_bounds__(512) void pass_b2_kernel(
    const int* __restrict__ tot, int* __restrict__ bucket_base)
{
    __shared__ int sh[512];
    const int t = threadIdx.x;
    const int i0 = 2 * t, i1 = 2 * t + 1;
    int v0 = (i0 < NBIN) ? tot[i0] : 0;
    int v1 = (i1 < NBIN) ? tot[i1] : 0;
    int ps = v0 + v1;
    sh[t] = ps;
    __syncthreads();
    for (int off = 1; off < 512; off <<= 1) {
        int add = (t >= off) ? sh[t - off] : 0;
        __syncthreads();
        sh[t] += add;
        __syncthreads();
    }
    int excl = sh[t] - ps;
    if (i0 <= NBIN) bucket_base[i0] = excl;
    if (i1 <= NBIN) bucket_base[i1] = excl + v0;     // i1==NBIN -> N_EDGES
}

// -------------------- Pass C: LDS counting-sort, coalesced write-out -----------
__global__ __launch_bounds__(256) void pass_c_kernel(
    const int* __restrict__ erow, const int* __restrict__ ecol,
    const float* __restrict__ eval_, const int* __restrict__ cntmat,
    const int* __restrict__ blockbase, const int* __restrict__ bucket_base,
    int2* __restrict__ tmp)
{
    __shared__ int2 skv[CHUNK];              // 28,576 B
    __shared__ unsigned short sbin[CHUNK];   // 7,144 B
    __shared__ int  cur[NBIN];               // 3,128 B
    __shared__ int  sdel[NBIN];              // 3,128 B
    __shared__ int  sscan[256];              // total ~50.2 KB -> 3 blocks/CU

    const int t = threadIdx.x;
    const int b = blockIdx.x;

    int c[BPTC];
    int ps = 0;
#pragma unroll
    for (int i = 0; i < BPTC; ++i) {
        int bin = t * BPTC + i;
        c[i] = (bin < NBIN) ? cntmat[(size_t)b * NBIN + bin] : 0;
        ps += c[i];
    }
    sscan[t] = ps;
    __syncthreads();
    for (int off = 1; off < 256; off <<= 1) {
        int add = (t >= off) ? sscan[t - off] : 0;
        __syncthreads();
        sscan[t] += add;
        __syncthreads();
    }
    int excl = sscan[t] - ps;
#pragma unroll
    for (int i = 0; i < BPTC; ++i) {
        int bin = t * BPTC + i;
        if (bin < NBIN) {
            cur[bin]  = excl;
            sdel[bin] = bucket_base[bin] + blockbase[(size_t)b * NBIN + bin] - excl;
            excl += c[i];
        }
    }
    __syncthreads();

    const int base = b * CHUNK;
    const int end  = min(base + CHUNK, N_EDGES);
    for (int i = base + t * 4; i < end; i += 1024) {
        int4   r = *(const int4*)(erow + i);
        int4   cc = *(const int4*)(ecol + i);
        float4 v = *(const float4*)(eval_ + i);
        int bin, pos;
        bin = r.x >> 7; pos = atomicAdd(&cur[bin], 1);
        skv[pos] = make_int2(cc.x | ((r.x & 127) << 17), __float_as_int(v.x));
        sbin[pos] = (unsigned short)bin;
        bin = r.y >> 7; pos = atomicAdd(&cur[bin], 1);
        skv[pos] = make_int2(cc.y | ((r.y & 127) << 17), __float_as_int(v.y));
        sbin[pos] = (unsigned short)bin;
        bin = r.z >> 7; pos = atomicAdd(&cur[bin], 1);
        skv[pos] = make_int2(cc.z | ((r.z & 127) << 17), __float_as_int(v.z));
        sbin[pos] = (unsigned short)bin;
        bin = r.w >> 7; pos = atomicAdd(&cur[bin], 1);
        skv[pos] = make_int2(cc.w | ((r.w & 127) << 17), __float_as_int(v.w));
        sbin[pos] = (unsigned short)bin;
    }
    __syncthreads();

    const int n = end - base;
    for (int i = t; i < n; i += 256) {
        int2 kv = skv[i];
        tmp[sdel[sbin[i]] + i] = kv;
    }
}

// -------------------- fused D+aggregate: per-128-row-bucket fine sort (LDS) ----
// + register-accumulated gather + bias. One 512-thr block per bucket.
__global__ __launch_bounds__(512) void fused_da_kernel(
    const int2* __restrict__ tmp, const int* __restrict__ bucket_base,
    const unsigned* __restrict__ h2, const float* __restrict__ bias,
    float* __restrict__ out)
{
    __shared__ int2 skv[CAP];      // 36,864 B sorted edges (col, val)
    __shared__ int  srow[RPB];
    __shared__ int  scnt[RPB];
    __shared__ int  cursor[RPB];   // total 38,400 B -> 4 blocks/CU

    const int t    = threadIdx.x;
    const int lane = t & 63;
    const int w    = t >> 6;       // wave 0..7
    const int j    = blockIdx.x;
    const int base = bucket_base[j];
    int n = bucket_base[j + 1] - base;
    if (n > CAP) n = CAP;          // safety (statistically unreachable)

    // fine histogram (128 bins)
    if (t < RPB) cursor[t] = 0;
    __syncthreads();
    for (int i = t; i < n; i += 512)
        atomicAdd(&cursor[tmp[base + i].x >> 17], 1);
    __syncthreads();
    if (t < RPB) { scnt[t] = cursor[t]; srow[t] = cursor[t]; }
    __syncthreads();
    for (int off = 1; off < RPB; off <<= 1) {
        int add = (t >= off && t < RPB) ? srow[t - off] : 0;
        __syncthreads();
        if (t < RPB) srow[t] += add;
        __syncthreads();
    }
    if (t < RPB) { int ex = srow[t] - scnt[t]; srow[t] = ex; cursor[t] = ex; }
    __syncthreads();

    // scatter into LDS sorted by fine row (tmp L2-hot re-read)
    for (int i = t; i < n; i += 512) {
        int2 p = tmp[base + i];
        int rl = p.x >> 17;
        int pos = atomicAdd(&cursor[rl], 1);
        skv[pos] = make_int2(p.x & 0x1FFFF, p.y);
    }
    __syncthreads();

    // aggregate: wave w handles rows w*16 .. w*16+15; lane owns feats {2l, 2l+1}
    const unsigned* hb = h2 + lane;
#pragma unroll 1
    for (int rr = w * 16; rr < w * 16 + 16; ++rr) {
        int gr = j * RPB + rr;
        if (gr >= N_NODES) break;               // wave-uniform
        int s = srow[rr];
        int end = s + scnt[rr];
        float ax = 0.f, ay = 0.f;

        int e = s;
        for (; e + 7 < end; e += 8) {
            int2 p0 = skv[e];
            int2 p1 = skv[e + 1];
            int2 p2 = skv[e + 2];
            int2 p3 = skv[e + 3];
            int2 p4 = skv[e + 4];
            int2 p5 = skv[e + 5];
            int2 p6 = skv[e + 6];
            int2 p7 = skv[e + 7];
            unsigned u0 = hb[(size_t)p0.x << 6];
            unsigned u1 = hb[(size_t)p1.x << 6];
            unsigned u2 = hb[(size_t)p2.x << 6];
            unsigned u3 = hb[(size_t)p3.x << 6];
            unsigned u4 = hb[(size_t)p4.x << 6];
            unsigned u5 = hb[(size_t)p5.x << 6];
            unsigned u6 = hb[(size_t)p6.x << 6];
            unsigned u7 = hb[(size_t)p7.x << 6];
            float v0 = __int_as_float(p0.y), v1 = __int_as_float(p1.y);
            float v2 = __int_as_float(p2.y), v3 = __int_as_float(p3.y);
            float v4 = __int_as_float(p4.y), v5 = __int_as_float(p5.y);
            float v6 = __int_as_float(p6.y), v7 = __int_as_float(p7.y);
            ax = fmaf(v0, __uint_as_float(u0 << 16), ax);
            ay = fmaf(v0, __uint_as_float(u0 & 0xFFFF0000u), ay);
            ax = fmaf(v1, __uint_as_float(u1 << 16), ax);
            ay = fmaf(v1, __uint_as_float(u1 & 0xFFFF0000u), ay);
            ax = fmaf(v2, __uint_as_float(u2 << 16), ax);
            ay = fmaf(v2, __uint_as_float(u2 & 0xFFFF0000u), ay);
            ax = fmaf(v3, __uint_as_float(u3 << 16), ax);
            ay = fmaf(v3, __uint_as_float(u3 & 0xFFFF0000u), ay);
            ax = fmaf(v4, __uint_as_float(u4 << 16), ax);
            ay = fmaf(v4, __uint_as_float(u4 & 0xFFFF0000u), ay);
            ax = fmaf(v5, __uint_as_float(u5 << 16), ax);
            ay = fmaf(v5, __uint_as_float(u5 & 0xFFFF0000u), ay);
            ax = fmaf(v6, __uint_as_float(u6 << 16), ax);
            ay = fmaf(v6, __uint_as_float(u6 & 0xFFFF0000u), ay);
            ax = fmaf(v7, __uint_as_float(u7 << 16), ax);
            ay = fmaf(v7, __uint_as_float(u7 & 0xFFFF0000u), ay);
        }
        for (; e < end; ++e) {
            int2 p0 = skv[e];
            unsigned u0 = hb[(size_t)p0.x << 6];
            float v0 = __int_as_float(p0.y);
            ax = fmaf(v0, __uint_as_float(u0 << 16), ax);
            ay = fmaf(v0, __uint_as_float(u0 & 0xFFFF0000u), ay);
        }

        float2 bb = *(const float2*)(bias + lane * 2);
        *(float2*)(out + (size_t)gr * OUT_F + lane * 2) =
            make_float2(ax + bb.x, ay + bb.y);
    }
}

// -------------------- launch --------------------
extern "C" void kernel_launch(void* const* d_in, const int* in_sizes, int n_in,
                              void* d_out, int out_size, void* d_ws, size_t ws_size,
                              hipStream_t stream)
{
    const float* x     = (const float*)d_in[0];
    const int*   erow  = (const int*)d_in[1];
    const int*   ecol  = (const int*)d_in[2];
    const float* eval_ = (const float*)d_in[3];
    const float* w     = (const float*)d_in[4];
    const float* bias  = (const float*)d_in[5];
    float*       out   = (float*)d_out;

    // workspace layout (bytes):
    //   h (bf16):    0          .. 25,600,000
    //   tmp:         25,600,000 .. 51,200,000
    //   cntmat:      51,200,000 .. 54,002,688   (896 x 782 int)
    //   blockbase:   54,002,688 .. 56,805,376
    //   tot:         56,805,376 .. 56,808,504 -> pad 56,812,000
    //   bucket_base: 56,812,000 .. 56,815,132 -> pad 56,816,000 (783 int)
    //   wbfF:        56,816,000 .. 56,881,536   (~56.9 MB)
    char* ws = (char*)d_ws;
    unsigned short* h           = (unsigned short*)(ws);
    int2*           tmp         = (int2*)(ws + 25600000);
    int*            cntmat      = (int*)(ws + 51200000);
    int*            blockbase   = (int*)(ws + 54002688);
    int*            tot         = (int*)(ws + 56805376);
    int*            bucket_base = (int*)(ws + 56812000);
    uint4*          wbfF        = (uint4*)(ws + 56816000);

    // 0) w -> frag-ordered bf16
    hipLaunchKernelGGL(conv_w_kernel, dim3(16), dim3(256), 0, stream, w, wbfF);

    // 1) fused: h = bf16(x@w) via MFMA  ||  coarse histogram (782 bins)
    hipLaunchKernelGGL(gemm_hist_kernel, dim3(GEMM_BLOCKS + NBC), dim3(256), 0, stream,
                       x, wbfF, h, erow, cntmat);

    // 2) scans
    hipLaunchKernelGGL(pass_b_kernel, dim3(NBIN), dim3(256), 0, stream,
                       cntmat, blockbase, tot);
    hipLaunchKernelGGL(pass_b2_kernel, dim3(1), dim3(512), 0, stream, tot, bucket_base);

    // 3) LDS counting-sort scatter into bucket-ordered tmp (coalesced writes)
    hipLaunchKernelGGL(pass_c_kernel, dim3(NBC), dim3(256), 0, stream,
                       erow, ecol, eval_, cntmat, blockbase, bucket_base, tmp);

    // 4) fused fine-sort + aggregate + bias
    hipLaunchKernelGGL(fused_da_kernel, dim3(NBIN), dim3(512), 0, stream,
                       tmp, bucket_base, (const unsigned*)h, bias, out);
}